// Round 3
// baseline (389.212 us; speedup 1.0000x reference)
//
#include <hip/hip_runtime.h>
#include <hip/hip_bf16.h>

// LigandCrossAttention fused bf16-MFMA implementation for gfx950, v3.
// B=16, S=2048, A=128, D_MODEL=512, H=8, Dh=64.
// v3: fused kernel = 256 thr / 32 s-rows / 40KB LDS -> 4 blocks/CU (16 waves),
//     dist stored fp16, 3-bit XOR swizzle everywhere, kvproj 128 blocks.

typedef __attribute__((ext_vector_type(8))) short short8;   // 8 x bf16 bits
typedef __attribute__((ext_vector_type(4))) float f32x4;
typedef __attribute__((ext_vector_type(4))) unsigned int u32x4;

#define MFMA16(a, b, c) __builtin_amdgcn_mfma_f32_16x16x32_bf16((a), (b), (c), 0, 0, 0)
#define LOG2E 1.44269504088896340736f

__device__ __forceinline__ unsigned int cvtpk(float lo, float hi) {
  unsigned int r;
  asm("v_cvt_pk_bf16_f32 %0, %1, %2" : "=v"(r) : "v"(lo), "v"(hi));
  return r;
}
__device__ __forceinline__ unsigned int pkf16(float lo, float hi) {  // 2xf32->2xf16 RTZ
  unsigned int r;
  asm("v_cvt_pkrtz_f16_f32 %0, %1, %2" : "=v"(r) : "v"(lo), "v"(hi));
  return r;
}
__device__ __forceinline__ float f16f(unsigned short u) {
  _Float16 h;
  __builtin_memcpy(&h, &u, 2);
  return (float)h;
}
__device__ __forceinline__ short f2bf1(float f) {
  return (short)(cvtpk(f, f) & 0xffffu);
}
__device__ __forceinline__ short f2bf(float f) {   // manual RNE (prep path)
  unsigned int u = __float_as_uint(f);
  u += 0x7FFFu + ((u >> 16) & 1u);
  return (short)(u >> 16);
}
__device__ __forceinline__ float bexp2(float x) {
  float r;
  asm("v_exp_f32 %0, %1" : "=v"(r) : "v"(x));
  return r;
}

// ---------------------------------------------------------------------------
// Kernel 1: prep. bid<256: weight transpose (fp32 [k][n] -> bf16 [n][k]);
//           bid==256: atom/mask bias bav2[b][h][a] (pre-scaled by log2e).
// ---------------------------------------------------------------------------
__global__ __launch_bounds__(256)
void prep_kernel(const float* __restrict__ Wq, const float* __restrict__ Wk,
                 const float* __restrict__ Wv, const float* __restrict__ Wo,
                 unsigned short* __restrict__ dst,
                 const int* __restrict__ types, const int* __restrict__ mask,
                 const float* __restrict__ bd, const float* __restrict__ aemb,
                 float* __restrict__ bav2) {
  const int bid = blockIdx.x;
  if (bid == 256) {
#pragma unroll
    for (int it = 0; it < 8; it++) {
      int t = it * 256 + threadIdx.x;  // 0..2047 = b*128 + a
      int msk = mask[t];
      int tp = types[t];
      int b = t >> 7, a = t & 127;
#pragma unroll
      for (int h = 0; h < 8; h++)
        bav2[((size_t)b * 8 + h) * 128 + a] =
            msk ? (aemb[tp * 8 + h] + bd[h]) * LOG2E : -1e30f;
    }
    return;
  }
  __shared__ float t[64][65];
  const int wsel = bid >> 6, tile = bid & 63;
  const float* src = (wsel == 0) ? Wq : (wsel == 1) ? Wk : (wsel == 2) ? Wv : Wo;
  unsigned short* d = dst + (size_t)wsel * 512 * 512;
  const int k0 = (tile >> 3) * 64, n0 = (tile & 7) * 64;
  const int c = threadIdx.x & 63, r4 = threadIdx.x >> 6;
#pragma unroll
  for (int i = 0; i < 16; i++) {
    int row = i * 4 + r4;
    t[row][c] = src[(size_t)(k0 + row) * 512 + n0 + c];
  }
  __syncthreads();
#pragma unroll
  for (int i = 0; i < 16; i++) {
    int row = i * 4 + r4;
    d[(size_t)(n0 + row) * 512 + k0 + c] = (unsigned short)f2bf(t[c][row]);
  }
}

// ---------------------------------------------------------------------------
// Kernel 2: K/V projection. grid=(2 [k|v], 16 [b], 4 [n-quarter]), 512 thr.
// K -> kbuf[b][h][a][d] bf16 ; V -> vtbuf[b][h][d][pos] (pi-permuted a-order).
// ---------------------------------------------------------------------------
__global__ __launch_bounds__(512)
void kvproj_kernel(const float* __restrict__ ligand,
                   const unsigned short* __restrict__ WkT,
                   const unsigned short* __restrict__ WvT,
                   const float* __restrict__ bk, const float* __restrict__ bv,
                   unsigned short* __restrict__ kbuf,
                   unsigned short* __restrict__ vtbuf) {
  __shared__ short st[128 * 64];
  char* sb = (char*)st;
  const int kv = blockIdx.x, b = blockIdx.y, nh = blockIdx.z;
  const unsigned short* WT = kv ? WvT : WkT;
  const float* bias = kv ? bv : bk;
  const int tid = threadIdx.x, lane = tid & 63, w = tid >> 6;
  const int c = lane & 15, g = lane >> 4;
  const int col = nh * 128 + w * 16 + c;  // this lane's output column
  const f32x4 fz = {0.f, 0.f, 0.f, 0.f};
  f32x4 acc[8];
#pragma unroll
  for (int i = 0; i < 8; i++) acc[i] = fz;
  const int srow = tid >> 2, sq = tid & 3;
  for (int kb = 0; kb < 8; kb++) {
    const float* src = ligand + ((size_t)(b * 128 + srow) * 512 + kb * 64 + sq * 16);
    float4 x0 = ((const float4*)src)[0];
    float4 x1 = ((const float4*)src)[1];
    float4 x2 = ((const float4*)src)[2];
    float4 x3 = ((const float4*)src)[3];
    uint4 v0, v1;
    v0.x = cvtpk(x0.x, x0.y); v0.y = cvtpk(x0.z, x0.w);
    v0.z = cvtpk(x1.x, x1.y); v0.w = cvtpk(x1.z, x1.w);
    v1.x = cvtpk(x2.x, x2.y); v1.y = cvtpk(x2.z, x2.w);
    v1.z = cvtpk(x3.x, x3.y); v1.w = cvtpk(x3.z, x3.w);
    *(uint4*)(sb + srow * 128 + ((sq * 32) ^ ((srow & 7) << 4))) = v0;
    *(uint4*)(sb + srow * 128 + ((sq * 32 + 16) ^ ((srow & 7) << 4))) = v1;
    __syncthreads();
#pragma unroll
    for (int kk = 0; kk < 64; kk += 32) {
      short8 bf = *(const short8*)(WT + (size_t)col * 512 + kb * 64 + kk + g * 8);
#pragma unroll
      for (int mt = 0; mt < 8; mt++) {
        int row = mt * 16 + c;
        short8 af = *(const short8*)(sb + row * 128 + ((kk * 2 + g * 16) ^ ((row & 7) << 4)));
        acc[mt] = MFMA16(af, bf, acc[mt]);
      }
    }
    __syncthreads();
  }
  {
    float bs = bias[col];
    int h = col >> 6, dd = col & 63;
#pragma unroll
    for (int mt = 0; mt < 8; mt++)
#pragma unroll
      for (int r = 0; r < 4; r++) {
        int a = mt * 16 + g * 4 + r;  // D-layout: row = 4*(lane>>4)+reg
        unsigned short us = (unsigned short)f2bf(acc[mt][r] + bs);
        if (!kv) {
          kbuf[((size_t)(b * 8 + h) * 128 + a) * 64 + dd] = us;
        } else {
          int pos = (mt >> 1) * 32 + g * 8 + (mt & 1) * 4 + r;  // pi-permuted
          vtbuf[((size_t)(b * 8 + h) * 64 + dd) * 128 + pos] = us;
        }
      }
  }
}

// ---------------------------------------------------------------------------
// Kernel 3: fused Q-proj + attention (wave -> 2 heads) + O-proj.
// grid=(64 s-tiles, 16 b), 256 thr, 40KB LDS -> 4 blocks/CU. 3 barriers.
// qao region (32KB): protein-stage [32][512]bf16 -> q [8 chunks][32][64]
// -> ao (same layout); all rows XOR-swizzled byte^=(row&7)<<4.
// ---------------------------------------------------------------------------
__global__ __launch_bounds__(256, 4)
void fused_kernel(const float* __restrict__ protein, const float* __restrict__ pcoord,
                  const float* __restrict__ lcoord, const float* __restrict__ Wdp,
                  const float* __restrict__ bq, const float* __restrict__ bo,
                  const unsigned short* __restrict__ WqT,
                  const unsigned short* __restrict__ WoT,
                  const unsigned short* __restrict__ kbuf,
                  const unsigned short* __restrict__ vtbuf,
                  const float* __restrict__ bav2, float* __restrict__ out) {
  __shared__ short8 qao_v[2048];                    // 32 KB
  __shared__ __align__(16) unsigned int distl[2048]; // 8 KB (fp16 dist [32][128])
  char* qb = (char*)qao_v;
  char* db = (char*)distl;

  const int b = blockIdx.y, s0 = blockIdx.x * 32;
  const int tid = threadIdx.x, lane = tid & 63, w = tid >> 6;
  const int c = lane & 15, g = lane >> 4;
  const f32x4 fz = {0.f, 0.f, 0.f, 0.f};

  // ---- Stage A: protein tile [32][512] fp32 -> bf16 LDS, row-XOR-swizzled ----
#pragma unroll
  for (int i = 0; i < 8; i++) {
    int idx = i * 256 + tid;  // 16B-granule index in the 32x512 tile
    const float* src = protein + (size_t)(b * 2048 + s0) * 512 + idx * 8;
    float4 x0 = ((const float4*)src)[0];
    float4 x1 = ((const float4*)src)[1];
    uint4 v;
    v.x = cvtpk(x0.x, x0.y); v.y = cvtpk(x0.z, x0.w);
    v.z = cvtpk(x1.x, x1.y); v.w = cvtpk(x1.z, x1.w);
    int row = idx >> 6, gran = idx & 63;
    *(uint4*)(qb + row * 1024 + ((gran * 16) ^ ((row & 7) << 4))) = v;
  }
  // ---- Stage B: dist[s][a] fp16 LDS (once per block), swizzled ----
  {
    int s = tid >> 3, t7 = tid & 7;
    const float* p3 = pcoord + (size_t)(b * 2048 + s0 + s) * 3;
    float px = p3[0], py = p3[1], pz = p3[2];
#pragma unroll
    for (int ii = 0; ii < 2; ii++) {
      uint4 dv;
#pragma unroll
      for (int jj = 0; jj < 4; jj++) {
        float dpair[2];
#pragma unroll
        for (int e = 0; e < 2; e++) {
          int a = t7 * 16 + ii * 8 + jj * 2 + e;
          const float* l3 = lcoord + (size_t)(b * 128 + a) * 3;
          float dx = px - l3[0], dy = py - l3[1], dz = pz - l3[2];
          dpair[e] = sqrtf(dx * dx + dy * dy + dz * dz);
        }
        ((unsigned int*)&dv)[jj] = pkf16(dpair[0], dpair[1]);
      }
      *(uint4*)(db + s * 256 + ((t7 * 32 + ii * 16) ^ ((s & 7) << 4))) = dv;
    }
  }
  __syncthreads();  // barrier 1

  // ---- Phase 1: Q-proj (q = P @ Wq + bq); per wave 128 n-cols ----
  f32x4 accq[2][8];
#pragma unroll
  for (int i = 0; i < 2; i++)
#pragma unroll
    for (int j = 0; j < 8; j++) accq[i][j] = fz;
  for (int kp = 0; kp < 16; kp++) {
    short8 bfr[8], afr[2];
#pragma unroll
    for (int nt = 0; nt < 8; nt++)
      bfr[nt] = *(const short8*)(WqT + (size_t)(w * 128 + nt * 16 + c) * 512 +
                                 kp * 32 + g * 8);
#pragma unroll
    for (int mt = 0; mt < 2; mt++) {
      int row = mt * 16 + c;
      afr[mt] = *(const short8*)(qb + row * 1024 +
                                 ((kp * 64 + g * 16) ^ ((row & 7) << 4)));
    }
#pragma unroll
    for (int nt = 0; nt < 8; nt++)
#pragma unroll
      for (int mt = 0; mt < 2; mt++)
        accq[mt][nt] = MFMA16(afr[mt], bfr[nt], accq[mt][nt]);
  }
  __syncthreads();  // barrier 2: protein reads done; q may overwrite region

  // q write: n = w*128+nt*16+c -> chunk n>>6, element sl = n&63;
  // byte = chunk*4096 + s*128 + ((sl*2) ^ ((s&7)<<4)).
#pragma unroll
  for (int nt = 0; nt < 8; nt++) {
    int n = w * 128 + nt * 16 + c;
    float bqv = bq[n];
    int chunk = n >> 6, sl = n & 63;
#pragma unroll
    for (int mt = 0; mt < 2; mt++)
#pragma unroll
      for (int r = 0; r < 4; r++) {
        int s = mt * 16 + g * 4 + r;
        *(short*)(qb + chunk * 4096 + s * 128 + ((sl * 2) ^ ((s & 7) << 4))) =
            f2bf1(accq[mt][nt][r] + bqv);
      }
  }
  // No barrier: each wave reads back only its own chunks (2w, 2w+1).

  // ---- Phase 2: attention; wave w handles heads 2w, 2w+1. Zero barriers. ----
  const float c1 = 0.125f * LOG2E;
  for (int hh = 0; hh < 2; hh++) {
    const int h = w * 2 + hh;
    const float wdh2 = Wdp[h] * LOG2E;
    const unsigned short* kb_h = kbuf + (size_t)(b * 8 + h) * 128 * 64;
    const unsigned short* vt_h = vtbuf + (size_t)(b * 8 + h) * 64 * 128;
    const float* bav_h = bav2 + (size_t)(b * 8 + h) * 128;

    short8 qf[2][2];
#pragma unroll
    for (int st = 0; st < 2; st++) {
      int s = st * 16 + c;
#pragma unroll
      for (int kq = 0; kq < 2; kq++)
        qf[st][kq] = *(const short8*)(qb + h * 4096 + s * 128 +
                                      ((kq * 64 + g * 16) ^ ((s & 7) << 4)));
    }
    // S^T = mfma(K, Q): lane axis = s, reg axis = a -> softmax lane-local.
    f32x4 sc[8][2];
#pragma unroll
    for (int i = 0; i < 8; i++)
#pragma unroll
      for (int j = 0; j < 2; j++) sc[i][j] = fz;
#pragma unroll
    for (int at = 0; at < 8; at++) {
      const unsigned short* kr = kb_h + (at * 16 + c) * 64;
      short8 kf0 = *(const short8*)(kr + g * 8);
      short8 kf1 = *(const short8*)(kr + 32 + g * 8);
#pragma unroll
      for (int st = 0; st < 2; st++) sc[at][st] = MFMA16(kf0, qf[st][0], sc[at][st]);
#pragma unroll
      for (int st = 0; st < 2; st++) sc[at][st] = MFMA16(kf1, qf[st][1], sc[at][st]);
    }
    // bias (scale, dist fp16, atom/mask; all log2-domain) + row max
    float mx[2] = {-3e38f, -3e38f};
#pragma unroll
    for (int at = 0; at < 8; at++) {
      f32x4 bv = *(const f32x4*)(bav_h + at * 16 + g * 4);
#pragma unroll
      for (int st = 0; st < 2; st++) {
        int s = st * 16 + c;
        uint2 du = *(const uint2*)(db + s * 256 +
                                   (((at * 32 + (g & 2) * 8)) ^ ((s & 7) << 4)) +
                                   (g & 1) * 8);
        float d0 = f16f((unsigned short)(du.x & 0xffff));
        float d1 = f16f((unsigned short)(du.x >> 16));
        float d2 = f16f((unsigned short)(du.y & 0xffff));
        float d3 = f16f((unsigned short)(du.y >> 16));
        f32x4 dd = {d0, d1, d2, d3};
#pragma unroll
        for (int r = 0; r < 4; r++) {
          float v = fmaf(sc[at][st][r], c1, fmaf(dd[r], wdh2, bv[r]));
          sc[at][st][r] = v;
          mx[st] = fmaxf(mx[st], v);
        }
      }
    }
#pragma unroll
    for (int st = 0; st < 2; st++) {
      mx[st] = fmaxf(mx[st], __shfl_xor(mx[st], 16));
      mx[st] = fmaxf(mx[st], __shfl_xor(mx[st], 32));
    }
    float sum[2] = {0.f, 0.f};
#pragma unroll
    for (int at = 0; at < 8; at++)
#pragma unroll
      for (int st = 0; st < 2; st++)
#pragma unroll
        for (int r = 0; r < 4; r++) {
          float p = bexp2(sc[at][st][r] - mx[st]);
          sc[at][st][r] = p;
          sum[st] += p;
        }
#pragma unroll
    for (int st = 0; st < 2; st++) {
      sum[st] += __shfl_xor(sum[st], 16);
      sum[st] += __shfl_xor(sum[st], 32);
    }
    float rinv[2];
#pragma unroll
    for (int st = 0; st < 2; st++) rinv[st] = 1.f / sum[st];

    // PV: out^T = mfma(V^T, P^T); P in registers (pi-permuted order).
    f32x4 pv[4][2];
#pragma unroll
    for (int i = 0; i < 4; i++)
#pragma unroll
      for (int j = 0; j < 2; j++) pv[i][j] = fz;
#pragma unroll
    for (int ch = 0; ch < 4; ch++) {
      short8 pf[2];
#pragma unroll
      for (int st = 0; st < 2; st++) {
        u32x4 up;
        up[0] = cvtpk(sc[2 * ch][st][0], sc[2 * ch][st][1]);
        up[1] = cvtpk(sc[2 * ch][st][2], sc[2 * ch][st][3]);
        up[2] = cvtpk(sc[2 * ch + 1][st][0], sc[2 * ch + 1][st][1]);
        up[3] = cvtpk(sc[2 * ch + 1][st][2], sc[2 * ch + 1][st][3]);
        pf[st] = __builtin_bit_cast(short8, up);
      }
#pragma unroll
      for (int dt = 0; dt < 4; dt++) {
        short8 vf = *(const short8*)(vt_h + (dt * 16 + c) * 128 + ch * 32 + g * 8);
#pragma unroll
        for (int st = 0; st < 2; st++) pv[dt][st] = MFMA16(vf, pf[st], pv[dt][st]);
      }
    }
    // ao write into chunk h (this wave's own q chunk, already consumed)
#pragma unroll
    for (int dt = 0; dt < 4; dt++) {
#pragma unroll
      for (int st = 0; st < 2; st++) {
        int s = st * 16 + c;
        uint2 wv;
        wv.x = cvtpk(pv[dt][st][0] * rinv[st], pv[dt][st][1] * rinv[st]);
        wv.y = cvtpk(pv[dt][st][2] * rinv[st], pv[dt][st][3] * rinv[st]);
        *(uint2*)(qb + h * 4096 + s * 128 + (((dt * 32 + g * 8)) ^ ((s & 7) << 4))) = wv;
      }
    }
  }
  __syncthreads();  // barrier 3: all ao chunks visible

  // ---- Phase 3: O-proj out^T = mfma(Wo^T_n, ao_s) ----
  f32x4 acco[8][2];
#pragma unroll
  for (int i = 0; i < 8; i++)
#pragma unroll
    for (int j = 0; j < 2; j++) acco[i][j] = fz;
  for (int kc = 0; kc < 16; kc++) {
    short8 af[8], bf[2];
#pragma unroll
    for (int nt = 0; nt < 8; nt++)
      af[nt] = *(const short8*)(WoT + (size_t)(w * 128 + nt * 16 + c) * 512 +
                                kc * 32 + g * 8);
#pragma unroll
    for (int st = 0; st < 2; st++) {
      int s = st * 16 + c;
      bf[st] = *(const short8*)(qb + (kc >> 1) * 4096 + s * 128 +
                                (((kc & 1) * 64 + g * 16) ^ ((s & 7) << 4)));
    }
#pragma unroll
    for (int nt = 0; nt < 8; nt++)
#pragma unroll
      for (int st = 0; st < 2; st++)
        acco[nt][st] = MFMA16(af[nt], bf[st], acco[nt][st]);
  }
#pragma unroll
  for (int nt = 0; nt < 8; nt++) {
    f32x4 bo4 = *(const f32x4*)(bo + w * 128 + nt * 16 + g * 4);
#pragma unroll
    for (int st = 0; st < 2; st++) {
      int s = st * 16 + c;
      f32x4 o;
#pragma unroll
      for (int r = 0; r < 4; r++) o[r] = acco[nt][st][r] + bo4[r];
      *(f32x4*)(out + (size_t)(b * 2048 + s0 + s) * 512 + w * 128 + nt * 16 + g * 4) = o;
    }
  }
}

// ---------------------------------------------------------------------------
extern "C" void kernel_launch(void* const* d_in, const int* in_sizes, int n_in,
                              void* d_out, int out_size, void* d_ws, size_t ws_size,
                              hipStream_t stream) {
  const float* protein = (const float*)d_in[0];
  const float* ligand  = (const float*)d_in[1];
  const float* pcoord  = (const float*)d_in[2];
  const float* lcoord  = (const float*)d_in[3];
  const int*   atypes  = (const int*)d_in[4];
  const int*   lmask   = (const int*)d_in[5];
  const float* Wq = (const float*)d_in[6];
  const float* bq = (const float*)d_in[7];
  const float* Wk = (const float*)d_in[8];
  const float* bk = (const float*)d_in[9];
  const float* Wv = (const float*)d_in[10];
  const float* bv = (const float*)d_in[11];
  const float* Wo = (const float*)d_in[12];
  const float* bo = (const float*)d_in[13];
  const float* Wd = (const float*)d_in[14];
  const float* bd = (const float*)d_in[15];
  const float* aemb = (const float*)d_in[16];

  char* ws = (char*)d_ws;
  const size_t WSLOT = (size_t)512 * 512 * 2;  // 512 KB per bf16 weight
  unsigned short* WqT = (unsigned short*)(ws + 0 * WSLOT);
  unsigned short* WkT = (unsigned short*)(ws + 1 * WSLOT);
  unsigned short* WvT = (unsigned short*)(ws + 2 * WSLOT);
  unsigned short* WoT = (unsigned short*)(ws + 3 * WSLOT);
  unsigned short* kbuf  = (unsigned short*)(ws + 4 * WSLOT);                // 2 MB
  unsigned short* vtbuf = (unsigned short*)(ws + 4 * WSLOT + (2u << 20));   // 2 MB
  float* bav2 = (float*)(ws + 4 * WSLOT + (4u << 20));                      // 64 KB

  prep_kernel<<<257, 256, 0, stream>>>(Wq, Wk, Wv, Wo, WqT,
                                       atypes, lmask, bd, aemb, bav2);
  kvproj_kernel<<<dim3(2, 16, 4), 512, 0, stream>>>(ligand, WkT, WvT, bk, bv,
                                                    kbuf, vtbuf);
  fused_kernel<<<dim3(64, 16), 256, 0, stream>>>(protein, pcoord, lcoord, Wd, bq, bo,
                                                 WqT, WoT, kbuf, vtbuf, bav2,
                                                 (float*)d_out);
}